// Round 18
// baseline (308.616 us; speedup 1.0000x reference)
//
#include <hip/hip_runtime.h>

typedef _Float16 f16;
typedef _Float16 f16x8 __attribute__((ext_vector_type(8)));
typedef _Float16 f16x4 __attribute__((ext_vector_type(4)));
typedef float f32x4 __attribute__((ext_vector_type(4)));
typedef float f32x16 __attribute__((ext_vector_type(16)));
typedef unsigned int u32x4 __attribute__((ext_vector_type(4)));

// HEAD_DIM=64 -> 64^-0.5 = 0.125; fold log2(e) so softmax uses exp2 directly
#define SCALE_Q (0.125f * 1.44269504088896f)

__device__ __forceinline__ f32x4 mfma16x16x32(f16x8 a, f16x8 b, f32x4 c) {
  return __builtin_amdgcn_mfma_f32_16x16x32_f16(a, b, c, 0, 0, 0);
}
__device__ __forceinline__ f32x16 mfma32x32x16(f16x8 a, f16x8 b, f32x16 c) {
  return __builtin_amdgcn_mfma_f32_32x32x16_f16(a, b, c, 0, 0, 0);
}

// 2^x via compiler-visible intrinsic (v_exp_f32 with hazard handling)
__device__ __forceinline__ float fexp2(float x) {
  return __builtin_amdgcn_exp2f(x);
}

typedef const __attribute__((address_space(1))) void* gptr1;
typedef __attribute__((address_space(3))) void* lptr3;
__device__ __forceinline__ void gload_lds16(const void* g, void* l) {
  __builtin_amdgcn_global_load_lds((gptr1)g, (lptr3)l, 16, 0, 0);
}

__device__ __forceinline__ unsigned pk2(float a, float b) {
  return __builtin_bit_cast(unsigned, __builtin_amdgcn_cvt_pkrtz(a, b));
}

// ---------------- fused prep: x cvt (blocks 0-4095), w_qkv^T (4096-7167),
// ---------------- w_out^T (7168-8191). Block-uniform branching.
__global__ __launch_bounds__(256)
void prep(const float* __restrict__ x, f16* __restrict__ xh,
          const float* __restrict__ w_qkv, f16* __restrict__ wqkvT,
          const float* __restrict__ w_out, f16* __restrict__ woutT) {
  __shared__ float tile[32][33];
  const int bid = blockIdx.x;
  const int tid = threadIdx.x;
  if (bid < 4096) {
    int i = bid * 256 + tid;
    float4 v = reinterpret_cast<const float4*>(x)[i];
    f16x4 o = {(f16)v.x, (f16)v.y, (f16)v.z, (f16)v.w};
    reinterpret_cast<f16x4*>(xh)[i] = o;
    return;
  }
  const float* in;
  f16* out;
  int bx, by, R, Cin;
  if (bid < 7168) {
    int t = bid - 4096;
    in = w_qkv; out = wqkvT; R = 1024; Cin = 3072;
    bx = (t % 96) * 32; by = (t / 96) * 32;
  } else {
    int t = bid - 7168;
    in = w_out; out = woutT; R = 1024; Cin = 1024;
    bx = (t % 32) * 32; by = (t / 32) * 32;
  }
  int tx = tid & 31, ty = tid >> 5;
#pragma unroll
  for (int i = ty; i < 32; i += 8)
    tile[i][tx] = in[(size_t)(by + i) * Cin + bx + tx];
  __syncthreads();
#pragma unroll
  for (int i = ty; i < 32; i += 8)
    out[(size_t)(bx + i) * R + by + tx] = (f16)tile[tx][i];
}

// ---------------- GEMM1: qkv projection, fused fragment-packing epilogue ----
__global__ __launch_bounds__(256)
void gemm_qkv(const f16* __restrict__ A, const f16* __restrict__ Bt,
              const float* __restrict__ bias, f16* __restrict__ qQ,
              f16* __restrict__ kP, f16* __restrict__ vP) {
  constexpr int BM = 128, BN = 128, BK = 32, K = 1024;
  __shared__ f16 As[BM * BK];
  __shared__ f16 Bs[BN * BK];
  const int tid = threadIdx.x;
  const int l = tid & 63;
  const int w = tid >> 6;
  const int wr = w >> 1, wc = w & 1;
  // bijective XCD remap: 768 blocks -> (mx in [0,32), ny in [0,24))
  const int bid = blockIdx.x;
  const int xcd = bid & 7, idx = bid >> 3;        // idx in [0,96)
  const int xg = xcd & 3, yg = xcd >> 2;
  const int mx = xg * 8 + (idx & 7);
  const int ny = yg * 12 + (idx >> 3);
  const int bm = mx * BM, bn = ny * BN;
  const int l15 = l & 15, lhi = l >> 4;

  f32x4 acc[4][4] = {};

  const char* Ab = (const char*)A;
  const char* Bb = (const char*)Bt;
  const size_t rowbytes = (size_t)K * 2;

  for (int kt = 0; kt < K; kt += BK) {
    __syncthreads();
#pragma unroll
    for (int c = 0; c < 2; ++c) {
      int o = tid * 16 + c * 4096;
      int r = o >> 6;
      int cb = o & 63;
      gload_lds16(Ab + (size_t)(bm + r) * rowbytes + (size_t)kt * 2 + cb, (char*)As + o);
      gload_lds16(Bb + (size_t)(bn + r) * rowbytes + (size_t)kt * 2 + cb, (char*)Bs + o);
    }
    __syncthreads();

    f16x8 af[4], bf[4];
#pragma unroll
    for (int i = 0; i < 4; ++i)
      af[i] = *reinterpret_cast<const f16x8*>(&As[(wr * 64 + i * 16 + l15) * BK + 8 * lhi]);
#pragma unroll
    for (int i = 0; i < 4; ++i)
      bf[i] = *reinterpret_cast<const f16x8*>(&Bs[(wc * 64 + i * 16 + l15) * BK + 8 * lhi]);
#pragma unroll
    for (int i = 0; i < 4; ++i)
#pragma unroll
      for (int j = 0; j < 4; ++j)
        acc[i][j] = mfma16x16x32(af[i], bf[j], acc[i][j]);
  }

  const int region = bn >> 10;   // block-uniform: 0=Q, 1=K, 2=V
#pragma unroll
  for (int i = 0; i < 4; ++i) {
#pragma unroll
    for (int j = 0; j < 4; ++j) {
      int gr0 = bm + wr * 64 + i * 16 + 4 * lhi;   // multiple of 4
      int gc = bn + wc * 64 + j * 16 + l15;
      float bia = bias[gc];
      if (region == 0) {
#pragma unroll
        for (int r = 0; r < 4; ++r) {
          float v = (acc[i][j][r] + bia) * SCALE_Q;
          qQ[(size_t)(gr0 + r) * 1024 + gc] = (f16)v;
        }
      } else if (region == 1) {
        int dloc = gc - 1024;
        int h = dloc >> 6, dd = dloc & 63;
        int kd = dd >> 4, hi8 = (dd >> 3) & 1, j8 = dd & 7;
        int bb = gr0 >> 11;
        int pair = bb * 16 + h;
#pragma unroll
        for (int r = 0; r < 4; ++r) {
          int key = (gr0 + r) & 2047;
          int t32 = key >> 5, l31k = key & 31;
          size_t idxp = ((((size_t)pair * 64 + t32) * 4 + kd) * 64 + (hi8 * 32 + l31k)) * 8 + j8;
          kP[idxp] = (f16)(acc[i][j][r] + bia);
        }
      } else {
        int dloc = gc - 2048;
        int h = dloc >> 6, dd = dloc & 63;
        int dhalf = dd >> 5, l31v = dd & 31;
        int bb = gr0 >> 11;
        int pair = bb * 16 + h;
        int key = gr0 & 2047;
        int t64 = key >> 6;
        int k6 = key & 63;
        int ks = k6 >> 4, hiv = (k6 >> 3) & 1, jv = k6 & 7;   // jv in {0,4}
        int rr = dhalf * 4 + ks;
        size_t idxp = ((((size_t)pair * 32 + t64) * 8 + rr) * 64 + (hiv * 32 + l31v)) * 8 + jv;
        f16x4 ov;
#pragma unroll
        for (int r = 0; r < 4; ++r) ov[r] = (f16)(acc[i][j][r] + bia);
        *reinterpret_cast<f16x4*>(&vP[idxp]) = ov;
      }
    }
  }
}

// ---------------- GEMM2: out[4096][1024] f32, BM=128 BN=64 (2 blocks/CU) ----
__global__ __launch_bounds__(256)
void gemm_out(const f16* __restrict__ A, const f16* __restrict__ Bt,
              const float* __restrict__ bias, float* __restrict__ outf) {
  constexpr int BM = 128, BN = 64, BK = 32, K = 1024, N = 1024;
  __shared__ f16 As[BM * BK];
  __shared__ f16 Bs[BN * BK];
  const int tid = threadIdx.x;
  const int l = tid & 63;
  const int w = tid >> 6;            // wave owns 32 rows x 64 cols
  // bijective XCD remap: 512 blocks -> (mx in [0,32), ny in [0,16))
  const int bid = blockIdx.x;
  const int xcd = bid & 7, idx = bid >> 3;   // idx in [0,64)
  const int mx = xcd * 4 + (idx & 3);
  const int ny = idx >> 2;
  const int bm = mx * BM, bn = ny * BN;
  const int l15 = l & 15, lhi = l >> 4;

  f32x4 acc[2][4] = {};

  const char* Ab = (const char*)A;
  const char* Bb = (const char*)Bt;
  const size_t rowbytes = (size_t)K * 2;

  for (int kt = 0; kt < K; kt += BK) {
    __syncthreads();
#pragma unroll
    for (int c = 0; c < 2; ++c) {
      int o = tid * 16 + c * 4096;
      int r = o >> 6;
      int cb = o & 63;
      gload_lds16(Ab + (size_t)(bm + r) * rowbytes + (size_t)kt * 2 + cb, (char*)As + o);
    }
    {
      int o = tid * 16;
      int r = o >> 6;
      int cb = o & 63;
      gload_lds16(Bb + (size_t)(bn + r) * rowbytes + (size_t)kt * 2 + cb, (char*)Bs + o);
    }
    __syncthreads();

    f16x8 af[2], bf[4];
#pragma unroll
    for (int i = 0; i < 2; ++i)
      af[i] = *reinterpret_cast<const f16x8*>(&As[(w * 32 + i * 16 + l15) * BK + 8 * lhi]);
#pragma unroll
    for (int j = 0; j < 4; ++j)
      bf[j] = *reinterpret_cast<const f16x8*>(&Bs[(j * 16 + l15) * BK + 8 * lhi]);
#pragma unroll
    for (int i = 0; i < 2; ++i)
#pragma unroll
      for (int j = 0; j < 4; ++j)
        acc[i][j] = mfma16x16x32(af[i], bf[j], acc[i][j]);
  }

#pragma unroll
  for (int i = 0; i < 2; ++i) {
#pragma unroll
    for (int j = 0; j < 4; ++j) {
      int gr0 = bm + w * 32 + i * 16 + 4 * lhi;
      int gc = bn + j * 16 + l15;
      float b = bias[gc];
#pragma unroll
      for (int r = 0; r < 4; ++r)
        outf[(size_t)(gr0 + r) * N + gc] = acc[i][j][r] + b;
    }
  }
}

// ---------------- flash attention v12: in-wave 2-tile software pipeline ----
// Packed K/V + static softmax (as round-13 best) + T15-style overlap: the body
// for tile t issues QK(t+1)'s MFMA cluster FIRST (operands prefetched a body
// ago), then runs softmax(t) on the previous scores while those MFMAs execute,
// then PV(t). Two score states (sA/sB) + two K states (akA/akB), statically
// named, 2-body unrolled. V loads split early(av0)/late(av1) to bound regs.
__global__ void attn_kernel(const f16* __restrict__ qQ, const f16* __restrict__ kP,
                            const f16* __restrict__ vP, f16* __restrict__ outh) {
  constexpr int T = 2048;
  __shared__ float mo[4096];          // [wq][lane][32] merged-O scratch (16 KB)
  __shared__ float MlBuf[2][64];      // grp1 partial l

  const int tid = threadIdx.x;
  const int l = tid & 63;
  const int w = tid >> 6;          // 0..3
  const int wq = w >> 1;           // q sub-tile
  const int grp = w & 1;           // KV half
  const int l31 = l & 31, hi = l >> 5;

  // (b,h) pair in LOW bits -> XCD L2 locality for K/V
  const int bid = blockIdx.x;
  const int pair = bid & 31;
  const int b = pair >> 4;
  const int h = pair & 15;
  const int qt = bid >> 5;          // 0..31; 64 q-rows per block

  const int q0 = qt * 64 + wq * 32;

  // Q fragments (B-operand): bq[kd] = Q[q0+l31][16kd + 8hi .. +7]  (pre-scaled)
  f16x8 bq[4];
  {
    const f16* qp = qQ + (size_t)(b * T + q0 + l31) * 1024 + h * 64 + hi * 8;
#pragma unroll
    for (int kd = 0; kd < 4; ++kd)
      bq[kd] = *reinterpret_cast<const f16x8*>(qp + kd * 16);
  }

  const f16* Kp = kP + (size_t)pair * 131072;   // [t32][kd][lane][8]
  const f16* Vp = vP + (size_t)pair * 131072;   // [t64][r][lane][8]

  f32x16 o0 = {}, o1 = {};
  float l_r = 0.f;
  const int tbase = grp * 16;
  const f32x16 vzero = {};

#define LOADK_TO(AK, T64)                                                      \
  do {                                                                         \
    _Pragma("unroll") for (int kt = 0; kt < 2; ++kt)                           \
    _Pragma("unroll") for (int kd = 0; kd < 4; ++kd)                           \
      AK[kt][kd] = *reinterpret_cast<const f16x8*>(                            \
          Kp + ((((size_t)(T64) * 2 + kt) * 4 + kd) * 64 + l) * 8);            \
  } while (0)

#define QK_INTO(S0, S1, AK)                                                    \
  do {                                                                         \
    S0 = vzero; S1 = vzero;                                                    \
    __builtin_amdgcn_s_setprio(1);                                             \
    _Pragma("unroll") for (int kd = 0; kd < 4; ++kd)                           \
      S0 = mfma32x32x16(AK[0][kd], bq[kd], S0);                                \
    _Pragma("unroll") for (int kd = 0; kd < 4; ++kd)                           \
      S1 = mfma32x32x16(AK[1][kd], bq[kd], S1);                                \
    __builtin_amdgcn_s_setprio(0);                                             \
  } while (0)

  // BODY for tile TT: issue QK(TT+1) into (SN0,SN1) from AKQ; prefetch K(TLOAD)
  // into AKL; softmax+pack (SC0,SC1) [overlaps QK MFMAs]; PV(TT).
#define BODY(SC0, SC1, SN0, SN1, AKQ, AKL, TT, TLOAD)                          \
  do {                                                                         \
    const int t64g = tbase + (TT);                                             \
    QK_INTO(SN0, SN1, AKQ);                                                    \
    LOADK_TO(AKL, tbase + (TLOAD));                                            \
    f16x8 av0[4];                                                              \
    _Pragma("unroll") for (int ks = 0; ks < 4; ++ks)                           \
      av0[ks] = *reinterpret_cast<const f16x8*>(                               \
          Vp + (((size_t)t64g * 8 + ks) * 64 + l) * 8);                        \
    float sm[16];                                                              \
    _Pragma("unroll") for (int r = 0; r < 16; ++r) {                           \
      SC0[r] = fexp2(SC0[r]);                                                  \
      SC1[r] = fexp2(SC1[r]);                                                  \
      sm[r] = SC0[r] + SC1[r];                                                 \
    }                                                                          \
    _Pragma("unroll") for (int st = 8; st > 0; st >>= 1)                       \
      _Pragma("unroll") for (int r = 0; r < st; ++r) sm[r] += sm[r + st];      \
    l_r += sm[0] + __shfl_xor(sm[0], 32);                                      \
    f16x8 bp[4];                                                               \
    _Pragma("unroll") for (int kt = 0; kt < 2; ++kt) {                         \
      _Pragma("unroll") for (int s2 = 0; s2 < 2; ++s2) {                       \
        u32x4 wd;                                                              \
        _Pragma("unroll") for (int u = 0; u < 2; ++u) {                        \
          float a0 = kt ? SC1[8 * s2 + 2 * u] : SC0[8 * s2 + 2 * u];           \
          float a1 = kt ? SC1[8 * s2 + 2 * u + 1] : SC0[8 * s2 + 2 * u + 1];   \
          float b0 = kt ? SC1[8 * s2 + 4 + 2 * u] : SC0[8 * s2 + 4 + 2 * u];   \
          float b1 = kt ? SC1[8 * s2 + 4 + 2 * u + 1] : SC0[8 * s2 + 4 + 2 * u + 1]; \
          unsigned wB = pk2(a0, a1);                                           \
          unsigned wA = pk2(b0, b1);                                           \
          unsigned oB = __shfl_xor(wB, 32);                                    \
          unsigned oA = __shfl_xor(wA, 32);                                    \
          wd[u]     = hi ? oA : wB;                                            \
          wd[2 + u] = hi ? wA : oB;                                            \
        }                                                                      \
        bp[2 * kt + s2] = __builtin_bit_cast(f16x8, wd);                       \
      }                                                                        \
    }                                                                          \
    f16x8 av1[4];                                                              \
    _Pragma("unroll") for (int ks = 0; ks < 4; ++ks)                           \
      av1[ks] = *reinterpret_cast<const f16x8*>(                               \
          Vp + (((size_t)t64g * 8 + 4 + ks) * 64 + l) * 8);                    \
    __builtin_amdgcn_s_setprio(1);                                             \
    _Pragma("unroll") for (int ks = 0; ks < 4; ++ks) {                         \
      o0 = mfma32x32x16(av0[ks], bp[ks], o0);                                  \
      o1 = mfma32x32x16(av1[ks], bp[ks], o1);                                  \
    }                                                                          \
    __builtin_amdgcn_s_setprio(0);                                             \
  } while (0)

  f16x8 akA[2][4], akB[2][4];
  f32x16 sA0, sA1, sB0, sB1;
  LOADK_TO(akA, tbase);
  QK_INTO(sA0, sA1, akA);        // tile 0 scores
  LOADK_TO(akB, tbase + 1);
#pragma unroll 1
  for (int t = 0; t < 16; t += 2) {
    BODY(sA0, sA1, sB0, sB1, akB, akA, t, (t + 2 < 16 ? t + 2 : 15));
    BODY(sB0, sB1, sA0, sA1, akA, akB, t + 1, (t + 3 < 16 ? t + 3 : 15));
  }

  // ---- merge the two KV-half partials (grp1 -> LDS, grp0 combines+stores) ----
  const int mbase = wq * 2048 + l * 32;
  if (grp == 1) {
#pragma unroll
    for (int k = 0; k < 8; ++k) {
      int ks = k ^ (l & 7);
      f32x4 v;
      if (k < 4) { v = f32x4{o0[4*k], o0[4*k+1], o0[4*k+2], o0[4*k+3]}; }
      else       { int r = 4*(k-4); v = f32x4{o1[r], o1[r+1], o1[r+2], o1[r+3]}; }
      *reinterpret_cast<f32x4*>(&mo[mbase + ks * 4]) = v;
    }
    MlBuf[wq][l] = l_r;
  }
  __syncthreads();
  if (grp == 0) {
    float inv = 1.0f / (l_r + MlBuf[wq][l]);
    f16* orow = outh + (size_t)(b * T + q0 + l31) * 1024 + h * 64;
#pragma unroll
    for (int k = 0; k < 8; ++k) {
      int ks = k ^ (l & 7);
      f32x4 ob = *reinterpret_cast<const f32x4*>(&mo[mbase + ks * 4]);
#pragma unroll
      for (int j = 0; j < 4; ++j) {
        int r = 4 * (k & 3) + j;
        int d = (r & 3) + 8 * (r >> 2) + 4 * hi;
        float own = (k < 4) ? o0[r] : o1[r];
        float val = (own + ob[j]) * inv;
        orow[(k < 4 ? d : d + 32)] = (f16)val;
      }
    }
  }
#undef LOADK_TO
#undef QK_INTO
#undef BODY
}

extern "C" void kernel_launch(void* const* d_in, const int* in_sizes, int n_in,
                              void* d_out, int out_size, void* d_ws, size_t ws_size,
                              hipStream_t stream) {
  const float* x      = (const float*)d_in[0];  // [2,2048,1024]
  const float* w_qkv  = (const float*)d_in[1];  // [1024,3072]
  const float* b_qkv  = (const float*)d_in[2];  // [3072]
  const float* w_out  = (const float*)d_in[3];  // [1024,1024]
  const float* b_out  = (const float*)d_in[4];  // [1024]
  float* out = (float*)d_out;                   // [2,2048,1024] f32

  char* ws = (char*)d_ws;
  // 0-8 xh | 8-14 wqkvT | 14-16 woutT | 16-24 qQ | 24-32 kP | 32-40 vP | 40-48 attnh
  f16* xh    = (f16*)(ws);                 //  8 MB
  f16* wqkvT = (f16*)(ws + 8388608);       //  6 MB
  f16* woutT = (f16*)(ws + 14680064);      //  2 MB
  f16* qQ    = (f16*)(ws + 16777216);      //  8 MB [4096][1024]
  f16* kP    = (f16*)(ws + 25165824);      //  8 MB packed K
  f16* vP    = (f16*)(ws + 33554432);      //  8 MB packed V
  f16* attnh = (f16*)(ws + 41943040);      //  8 MB

  prep<<<8192, 256, 0, stream>>>(x, xh, w_qkv, wqkvT, w_out, woutT);
  gemm_qkv<<<768, 256, 0, stream>>>(xh, wqkvT, b_qkv, qQ, kP, vP);
  attn_kernel<<<1024, 256, 0, stream>>>(qQ, kP, vP, attnh);
  gemm_out<<<512, 256, 0, stream>>>(attnh, woutT, b_out, out);
}

// Round 19
// 118.426 us; speedup vs baseline: 2.6060x; 2.6060x over previous
//
#include <hip/hip_runtime.h>

typedef _Float16 f16;
typedef _Float16 f16x8 __attribute__((ext_vector_type(8)));
typedef _Float16 f16x4 __attribute__((ext_vector_type(4)));
typedef float f32x4 __attribute__((ext_vector_type(4)));
typedef float f32x16 __attribute__((ext_vector_type(16)));
typedef unsigned int u32x4 __attribute__((ext_vector_type(4)));

// HEAD_DIM=64 -> 64^-0.5 = 0.125; fold log2(e) so softmax uses exp2 directly
#define SCALE_Q (0.125f * 1.44269504088896f)

__device__ __forceinline__ f32x4 mfma16x16x32(f16x8 a, f16x8 b, f32x4 c) {
  return __builtin_amdgcn_mfma_f32_16x16x32_f16(a, b, c, 0, 0, 0);
}
__device__ __forceinline__ f32x16 mfma32x32x16(f16x8 a, f16x8 b, f32x16 c) {
  return __builtin_amdgcn_mfma_f32_32x32x16_f16(a, b, c, 0, 0, 0);
}

// 2^x via compiler-visible intrinsic (v_exp_f32 with hazard handling)
__device__ __forceinline__ float fexp2(float x) {
  return __builtin_amdgcn_exp2f(x);
}

typedef const __attribute__((address_space(1))) void* gptr1;
typedef __attribute__((address_space(3))) void* lptr3;
__device__ __forceinline__ void gload_lds16(const void* g, void* l) {
  __builtin_amdgcn_global_load_lds((gptr1)g, (lptr3)l, 16, 0, 0);
}

__device__ __forceinline__ unsigned pk2(float a, float b) {
  return __builtin_bit_cast(unsigned, __builtin_amdgcn_cvt_pkrtz(a, b));
}

// ---------------- fused prep: x cvt (blocks 0-4095), w_qkv^T (4096-7167),
// ---------------- w_out^T (7168-8191). Block-uniform branching.
__global__ __launch_bounds__(256)
void prep(const float* __restrict__ x, f16* __restrict__ xh,
          const float* __restrict__ w_qkv, f16* __restrict__ wqkvT,
          const float* __restrict__ w_out, f16* __restrict__ woutT) {
  __shared__ float tile[32][33];
  const int bid = blockIdx.x;
  const int tid = threadIdx.x;
  if (bid < 4096) {
    int i = bid * 256 + tid;
    float4 v = reinterpret_cast<const float4*>(x)[i];
    f16x4 o = {(f16)v.x, (f16)v.y, (f16)v.z, (f16)v.w};
    reinterpret_cast<f16x4*>(xh)[i] = o;
    return;
  }
  const float* in;
  f16* out;
  int bx, by, R, Cin;
  if (bid < 7168) {
    int t = bid - 4096;
    in = w_qkv; out = wqkvT; R = 1024; Cin = 3072;
    bx = (t % 96) * 32; by = (t / 96) * 32;
  } else {
    int t = bid - 7168;
    in = w_out; out = woutT; R = 1024; Cin = 1024;
    bx = (t % 32) * 32; by = (t / 32) * 32;
  }
  int tx = tid & 31, ty = tid >> 5;
#pragma unroll
  for (int i = ty; i < 32; i += 8)
    tile[i][tx] = in[(size_t)(by + i) * Cin + bx + tx];
  __syncthreads();
#pragma unroll
  for (int i = ty; i < 32; i += 8)
    out[(size_t)(bx + i) * R + by + tx] = (f16)tile[tx][i];
}

// ---------------- GEMM1: qkv projection, fused fragment-packing epilogue ----
__global__ __launch_bounds__(256)
void gemm_qkv(const f16* __restrict__ A, const f16* __restrict__ Bt,
              const float* __restrict__ bias, f16* __restrict__ qQ,
              f16* __restrict__ kP, f16* __restrict__ vP) {
  constexpr int BM = 128, BN = 128, BK = 32, K = 1024;
  __shared__ f16 As[BM * BK];
  __shared__ f16 Bs[BN * BK];
  const int tid = threadIdx.x;
  const int l = tid & 63;
  const int w = tid >> 6;
  const int wr = w >> 1, wc = w & 1;
  // bijective XCD remap: 768 blocks -> (mx in [0,32), ny in [0,24))
  const int bid = blockIdx.x;
  const int xcd = bid & 7, idx = bid >> 3;        // idx in [0,96)
  const int xg = xcd & 3, yg = xcd >> 2;
  const int mx = xg * 8 + (idx & 7);
  const int ny = yg * 12 + (idx >> 3);
  const int bm = mx * BM, bn = ny * BN;
  const int l15 = l & 15, lhi = l >> 4;

  f32x4 acc[4][4] = {};

  const char* Ab = (const char*)A;
  const char* Bb = (const char*)Bt;
  const size_t rowbytes = (size_t)K * 2;

  for (int kt = 0; kt < K; kt += BK) {
    __syncthreads();
#pragma unroll
    for (int c = 0; c < 2; ++c) {
      int o = tid * 16 + c * 4096;
      int r = o >> 6;
      int cb = o & 63;
      gload_lds16(Ab + (size_t)(bm + r) * rowbytes + (size_t)kt * 2 + cb, (char*)As + o);
      gload_lds16(Bb + (size_t)(bn + r) * rowbytes + (size_t)kt * 2 + cb, (char*)Bs + o);
    }
    __syncthreads();

    f16x8 af[4], bf[4];
#pragma unroll
    for (int i = 0; i < 4; ++i)
      af[i] = *reinterpret_cast<const f16x8*>(&As[(wr * 64 + i * 16 + l15) * BK + 8 * lhi]);
#pragma unroll
    for (int i = 0; i < 4; ++i)
      bf[i] = *reinterpret_cast<const f16x8*>(&Bs[(wc * 64 + i * 16 + l15) * BK + 8 * lhi]);
#pragma unroll
    for (int i = 0; i < 4; ++i)
#pragma unroll
      for (int j = 0; j < 4; ++j)
        acc[i][j] = mfma16x16x32(af[i], bf[j], acc[i][j]);
  }

  const int region = bn >> 10;   // block-uniform: 0=Q, 1=K, 2=V
#pragma unroll
  for (int i = 0; i < 4; ++i) {
#pragma unroll
    for (int j = 0; j < 4; ++j) {
      int gr0 = bm + wr * 64 + i * 16 + 4 * lhi;   // multiple of 4
      int gc = bn + wc * 64 + j * 16 + l15;
      float bia = bias[gc];
      if (region == 0) {
#pragma unroll
        for (int r = 0; r < 4; ++r) {
          float v = (acc[i][j][r] + bia) * SCALE_Q;
          qQ[(size_t)(gr0 + r) * 1024 + gc] = (f16)v;
        }
      } else if (region == 1) {
        int dloc = gc - 1024;
        int h = dloc >> 6, dd = dloc & 63;
        int kd = dd >> 4, hi8 = (dd >> 3) & 1, j8 = dd & 7;
        int bb = gr0 >> 11;
        int pair = bb * 16 + h;
#pragma unroll
        for (int r = 0; r < 4; ++r) {
          int key = (gr0 + r) & 2047;
          int t32 = key >> 5, l31k = key & 31;
          size_t idxp = ((((size_t)pair * 64 + t32) * 4 + kd) * 64 + (hi8 * 32 + l31k)) * 8 + j8;
          kP[idxp] = (f16)(acc[i][j][r] + bia);
        }
      } else {
        int dloc = gc - 2048;
        int h = dloc >> 6, dd = dloc & 63;
        int dhalf = dd >> 5, l31v = dd & 31;
        int bb = gr0 >> 11;
        int pair = bb * 16 + h;
        int key = gr0 & 2047;
        int t64 = key >> 6;
        int k6 = key & 63;
        int ks = k6 >> 4, hiv = (k6 >> 3) & 1, jv = k6 & 7;   // jv in {0,4}
        int rr = dhalf * 4 + ks;
        size_t idxp = ((((size_t)pair * 32 + t64) * 8 + rr) * 64 + (hiv * 32 + l31v)) * 8 + jv;
        f16x4 ov;
#pragma unroll
        for (int r = 0; r < 4; ++r) ov[r] = (f16)(acc[i][j][r] + bia);
        *reinterpret_cast<f16x4*>(&vP[idxp]) = ov;
      }
    }
  }
}

// ---------------- GEMM2: out[4096][1024] f32, BM=128 BN=64 (2 blocks/CU) ----
__global__ __launch_bounds__(256)
void gemm_out(const f16* __restrict__ A, const f16* __restrict__ Bt,
              const float* __restrict__ bias, float* __restrict__ outf) {
  constexpr int BM = 128, BN = 64, BK = 32, K = 1024, N = 1024;
  __shared__ f16 As[BM * BK];
  __shared__ f16 Bs[BN * BK];
  const int tid = threadIdx.x;
  const int l = tid & 63;
  const int w = tid >> 6;            // wave owns 32 rows x 64 cols
  // bijective XCD remap: 512 blocks -> (mx in [0,32), ny in [0,16))
  const int bid = blockIdx.x;
  const int xcd = bid & 7, idx = bid >> 3;   // idx in [0,64)
  const int mx = xcd * 4 + (idx & 3);
  const int ny = idx >> 2;
  const int bm = mx * BM, bn = ny * BN;
  const int l15 = l & 15, lhi = l >> 4;

  f32x4 acc[2][4] = {};

  const char* Ab = (const char*)A;
  const char* Bb = (const char*)Bt;
  const size_t rowbytes = (size_t)K * 2;

  for (int kt = 0; kt < K; kt += BK) {
    __syncthreads();
#pragma unroll
    for (int c = 0; c < 2; ++c) {
      int o = tid * 16 + c * 4096;
      int r = o >> 6;
      int cb = o & 63;
      gload_lds16(Ab + (size_t)(bm + r) * rowbytes + (size_t)kt * 2 + cb, (char*)As + o);
    }
    {
      int o = tid * 16;
      int r = o >> 6;
      int cb = o & 63;
      gload_lds16(Bb + (size_t)(bn + r) * rowbytes + (size_t)kt * 2 + cb, (char*)Bs + o);
    }
    __syncthreads();

    f16x8 af[2], bf[4];
#pragma unroll
    for (int i = 0; i < 2; ++i)
      af[i] = *reinterpret_cast<const f16x8*>(&As[(w * 32 + i * 16 + l15) * BK + 8 * lhi]);
#pragma unroll
    for (int j = 0; j < 4; ++j)
      bf[j] = *reinterpret_cast<const f16x8*>(&Bs[(j * 16 + l15) * BK + 8 * lhi]);
#pragma unroll
    for (int i = 0; i < 2; ++i)
#pragma unroll
      for (int j = 0; j < 4; ++j)
        acc[i][j] = mfma16x16x32(af[i], bf[j], acc[i][j]);
  }

#pragma unroll
  for (int i = 0; i < 2; ++i) {
#pragma unroll
    for (int j = 0; j < 4; ++j) {
      int gr0 = bm + w * 32 + i * 16 + 4 * lhi;
      int gc = bn + j * 16 + l15;
      float b = bias[gc];
#pragma unroll
      for (int r = 0; r < 4; ++r)
        outf[(size_t)(gr0 + r) * N + gc] = acc[i][j][r] + b;
    }
  }
}

// ---------------- flash attention v13: v11 + per-half softmax/PV interleave ----
// Same states as round-17 v11 (proven 57.5us): one score pair (s0,s1), K
// ping-pong prefetch. NEW: per-tile phases reordered so softmax(s0) issues
// while QK(s1)'s MFMAs execute, and softmax(s1) issues while PV(keys 0-31)
// executes. sched_barrier(0) pins the issue order (compiler otherwise hoists
// pure VALU across setprio). Zero additional register state.
__global__ __launch_bounds__(256, 2)
void attn_kernel(const f16* __restrict__ qQ, const f16* __restrict__ kP,
                 const f16* __restrict__ vP, f16* __restrict__ outh) {
  constexpr int T = 2048;
  __shared__ float mo[4096];          // [wq][lane][32] merged-O scratch (16 KB)
  __shared__ float MlBuf[2][64];      // grp1 partial l

  const int tid = threadIdx.x;
  const int l = tid & 63;
  const int w = tid >> 6;          // 0..3
  const int wq = w >> 1;           // q sub-tile
  const int grp = w & 1;           // KV half
  const int l31 = l & 31, hi = l >> 5;

  // (b,h) pair in LOW bits -> XCD L2 locality for K/V
  const int bid = blockIdx.x;
  const int pair = bid & 31;
  const int b = pair >> 4;
  const int h = pair & 15;
  const int qt = bid >> 5;          // 0..31; 64 q-rows per block

  const int q0 = qt * 64 + wq * 32;

  // Q fragments (B-operand): bq[kd] = Q[q0+l31][16kd + 8hi .. +7]  (pre-scaled)
  f16x8 bq[4];
  {
    const f16* qp = qQ + (size_t)(b * T + q0 + l31) * 1024 + h * 64 + hi * 8;
#pragma unroll
    for (int kd = 0; kd < 4; ++kd)
      bq[kd] = *reinterpret_cast<const f16x8*>(qp + kd * 16);
  }

  const f16* Kp = kP + (size_t)pair * 131072;   // [t32][kd][lane][8]
  const f16* Vp = vP + (size_t)pair * 131072;   // [t64][r][lane][8]

  f32x16 o0 = {}, o1 = {};
  float l_r = 0.f;
  const int tbase = grp * 16;

#define LOADK_TO(AK, T64)                                                      \
  do {                                                                         \
    _Pragma("unroll") for (int kt = 0; kt < 2; ++kt)                           \
    _Pragma("unroll") for (int kd = 0; kd < 4; ++kd)                           \
      AK[kt][kd] = *reinterpret_cast<const f16x8*>(                            \
          Kp + ((((size_t)(T64) * 2 + kt) * 4 + kd) * 64 + l) * 8);            \
  } while (0)

  // pack one 32-key half (S) into bp0/bp1 (B-operand fragments)
#define PACK_HALF(S, BP0, BP1)                                                 \
  do {                                                                         \
    _Pragma("unroll") for (int s2 = 0; s2 < 2; ++s2) {                         \
      u32x4 wd;                                                                \
      _Pragma("unroll") for (int u = 0; u < 2; ++u) {                          \
        float a0 = S[8 * s2 + 2 * u];                                          \
        float a1 = S[8 * s2 + 2 * u + 1];                                      \
        float b0 = S[8 * s2 + 4 + 2 * u];                                      \
        float b1 = S[8 * s2 + 4 + 2 * u + 1];                                  \
        unsigned wB = pk2(a0, a1);                                             \
        unsigned wA = pk2(b0, b1);                                             \
        unsigned oB = __shfl_xor(wB, 32);                                      \
        unsigned oA = __shfl_xor(wA, 32);                                      \
        wd[u]     = hi ? oA : wB;                                              \
        wd[2 + u] = hi ? wA : oB;                                              \
      }                                                                        \
      if (s2 == 0) BP0 = __builtin_bit_cast(f16x8, wd);                        \
      else         BP1 = __builtin_bit_cast(f16x8, wd);                        \
    }                                                                          \
  } while (0)

#define TILE_BODY(AKC, AKN, TT, TN)                                            \
  do {                                                                         \
    const int t64g = tbase + (TT);                                             \
    /* V fragments issued early; latency hides under QK + softmax(s0) */       \
    f16x8 av0[4], av1[4];                                                      \
    _Pragma("unroll") for (int ks = 0; ks < 4; ++ks) {                         \
      av0[ks] = *reinterpret_cast<const f16x8*>(                               \
          Vp + (((size_t)t64g * 8 + ks) * 64 + l) * 8);                        \
      av1[ks] = *reinterpret_cast<const f16x8*>(                               \
          Vp + (((size_t)t64g * 8 + 4 + ks) * 64 + l) * 8);                    \
    }                                                                          \
    f32x16 s0 = {}, s1 = {};                                                   \
    __builtin_amdgcn_s_setprio(1);                                             \
    _Pragma("unroll") for (int kd = 0; kd < 4; ++kd)                           \
      s0 = mfma32x32x16(AKC[0][kd], bq[kd], s0);                               \
    _Pragma("unroll") for (int kd = 0; kd < 4; ++kd)                           \
      s1 = mfma32x32x16(AKC[1][kd], bq[kd], s1);                               \
    __builtin_amdgcn_s_setprio(0);                                             \
    __builtin_amdgcn_sched_barrier(0);  /* pin: QK issued before softmax(s0) */\
    LOADK_TO(AKN, tbase + (TN));        /* prefetch next tile's K */           \
    /* softmax(s0) on VALU overlaps QK(s1) executing on MFMA pipe */           \
    float sm0[16];                                                             \
    _Pragma("unroll") for (int r = 0; r < 16; ++r) {                           \
      s0[r] = fexp2(s0[r]);                                                    \
      sm0[r] = s0[r];                                                          \
    }                                                                          \
    _Pragma("unroll") for (int st = 8; st > 0; st >>= 1)                       \
      _Pragma("unroll") for (int r = 0; r < st; ++r) sm0[r] += sm0[r + st];    \
    f16x8 bp0, bp1;                                                            \
    PACK_HALF(s0, bp0, bp1);                                                   \
    /* PV half 0 (keys 0-31) */                                                \
    __builtin_amdgcn_s_setprio(1);                                             \
    o0 = mfma32x32x16(av0[0], bp0, o0);                                        \
    o1 = mfma32x32x16(av1[0], bp0, o1);                                        \
    o0 = mfma32x32x16(av0[1], bp1, o0);                                        \
    o1 = mfma32x32x16(av1[1], bp1, o1);                                        \
    __builtin_amdgcn_s_setprio(0);                                             \
    __builtin_amdgcn_sched_barrier(0);  /* pin: PV0 issued before softmax(s1)*/\
    /* softmax(s1) on VALU overlaps PV0 executing on MFMA pipe */              \
    float sm1[16];                                                             \
    _Pragma("unroll") for (int r = 0; r < 16; ++r) {                           \
      s1[r] = fexp2(s1[r]);                                                    \
      sm1[r] = s1[r];                                                          \
    }                                                                          \
    _Pragma("unroll") for (int st = 8; st > 0; st >>= 1)                       \
      _Pragma("unroll") for (int r = 0; r < st; ++r) sm1[r] += sm1[r + st];    \
    float lp = sm0[0] + sm1[0];                                                \
    l_r += lp + __shfl_xor(lp, 32);                                            \
    f16x8 bp2, bp3;                                                            \
    PACK_HALF(s1, bp2, bp3);                                                   \
    /* PV half 1 (keys 32-63) */                                               \
    __builtin_amdgcn_s_setprio(1);                                             \
    o0 = mfma32x32x16(av0[2], bp2, o0);                                        \
    o1 = mfma32x32x16(av1[2], bp2, o1);                                        \
    o0 = mfma32x32x16(av0[3], bp3, o0);                                        \
    o1 = mfma32x32x16(av1[3], bp3, o1);                                        \
    __builtin_amdgcn_s_setprio(0);                                             \
  } while (0)

  f16x8 akA[2][4], akB[2][4];
  LOADK_TO(akA, tbase);
#pragma unroll 1
  for (int t = 0; t < 16; t += 2) {
    TILE_BODY(akA, akB, t, t + 1);
    TILE_BODY(akB, akA, t + 1, (t + 2 < 16 ? t + 2 : 15));
  }

  // ---- merge the two KV-half partials (grp1 -> LDS, grp0 combines+stores) ----
  const int mbase = wq * 2048 + l * 32;
  if (grp == 1) {
#pragma unroll
    for (int k = 0; k < 8; ++k) {
      int ks = k ^ (l & 7);
      f32x4 v;
      if (k < 4) { v = f32x4{o0[4*k], o0[4*k+1], o0[4*k+2], o0[4*k+3]}; }
      else       { int r = 4*(k-4); v = f32x4{o1[r], o1[r+1], o1[r+2], o1[r+3]}; }
      *reinterpret_cast<f32x4*>(&mo[mbase + ks * 4]) = v;
    }
    MlBuf[wq][l] = l_r;
  }
  __syncthreads();
  if (grp == 0) {
    float inv = 1.0f / (l_r + MlBuf[wq][l]);
    f16* orow = outh + (size_t)(b * T + q0 + l31) * 1024 + h * 64;
#pragma unroll
    for (int k = 0; k < 8; ++k) {
      int ks = k ^ (l & 7);
      f32x4 ob = *reinterpret_cast<const f32x4*>(&mo[mbase + ks * 4]);
#pragma unroll
      for (int j = 0; j < 4; ++j) {
        int r = 4 * (k & 3) + j;
        int d = (r & 3) + 8 * (r >> 2) + 4 * hi;
        float own = (k < 4) ? o0[r] : o1[r];
        float val = (own + ob[j]) * inv;
        orow[(k < 4 ? d : d + 32)] = (f16)val;
      }
    }
  }
#undef LOADK_TO
#undef PACK_HALF
#undef TILE_BODY
}

extern "C" void kernel_launch(void* const* d_in, const int* in_sizes, int n_in,
                              void* d_out, int out_size, void* d_ws, size_t ws_size,
                              hipStream_t stream) {
  const float* x      = (const float*)d_in[0];  // [2,2048,1024]
  const float* w_qkv  = (const float*)d_in[1];  // [1024,3072]
  const float* b_qkv  = (const float*)d_in[2];  // [3072]
  const float* w_out  = (const float*)d_in[3];  // [1024,1024]
  const float* b_out  = (const float*)d_in[4];  // [1024]
  float* out = (float*)d_out;                   // [2,2048,1024] f32

  char* ws = (char*)d_ws;
  // 0-8 xh | 8-14 wqkvT | 14-16 woutT | 16-24 qQ | 24-32 kP | 32-40 vP | 40-48 attnh
  f16* xh    = (f16*)(ws);                 //  8 MB
  f16* wqkvT = (f16*)(ws + 8388608);       //  6 MB
  f16* woutT = (f16*)(ws + 14680064);      //  2 MB
  f16* qQ    = (f16*)(ws + 16777216);      //  8 MB [4096][1024]
  f16* kP    = (f16*)(ws + 25165824);      //  8 MB packed K
  f16* vP    = (f16*)(ws + 33554432);      //  8 MB packed V
  f16* attnh = (f16*)(ws + 41943040);      //  8 MB

  prep<<<8192, 256, 0, stream>>>(x, xh, w_qkv, wqkvT, w_out, woutT);
  gemm_qkv<<<768, 256, 0, stream>>>(xh, wqkvT, b_qkv, qQ, kP, vP);
  attn_kernel<<<1024, 256, 0, stream>>>(qQ, kP, vP, attnh);
  gemm_out<<<512, 256, 0, stream>>>(attnh, woutT, b_out, out);
}